// Round 13
// baseline (58.217 us; speedup 1.0000x reference)
//
#include <hip/hip_runtime.h>
#include <hip/hip_fp16.h>
#include <math.h>

// ---------------------------------------------------------------------------
// SuperCKAN forward:
//   conv1 (k=5, grid5, n=12)  + pool -> (256,12,12,12)
//   conv2 (k=4, grid10, n=12) + pool -> (256,144,4,4)
//   conv3 (k=3, grid10, n=24) + pool -> (256,3456)
//   fc: x @ (w2@w1)^T + (b1@w2^T + b2) -> (256,10)
//
// R12: f16 weight tables, 4th attempt -- with inline-asm v_fma_mix_f32
// (VOP3P: fma(f16 hi/lo of VGPR, f32, f32) in ONE instr). VALU count is
// IDENTICAL to the fp32 kernel (no cvt chain -- R10's failure mode), LDS
// reads/element drop 15->10 (N=12) and 30->15 (N=24). Rows padded to 32B
// (N=12) / 48B (N=24) so every ds_read is 16B-aligned. acc stays a plain
// literal-indexed local array (R7/R9 scratch lesson).
// R11 structure kept verbatim: 4 launches, in-LDS table build from raw
// inputs, Wf=w2@w1 overlapped with conv1, bias folded into fc.
// f16 numerics pre-validated: R9/R10 passed at absmax 9.77e-4 (thr 5.2e-3).
// ---------------------------------------------------------------------------

#define B_BATCH 256

// packed-f16 fma: acc += f16(lo/hi of pk) * cf   (one VOP3P each)
#define FMIX_LO(a, pk, cf) \
    asm("v_fma_mix_f32 %0, %1, %2, %0 op_sel:[0,0,0] op_sel_hi:[1,0,0]" \
        : "+v"(a) : "v"(pk), "v"(cf))
#define FMIX_HI(a, pk, cf) \
    asm("v_fma_mix_f32 %0, %1, %2, %0 op_sel:[1,0,0] op_sel_hi:[1,0,0]" \
        : "+v"(a) : "v"(pk), "v"(cf))

// one packed row (12 ch in 6 u32, rows padded to 8 u32 = 32B), scaled by cf
#define ROWH12(rp, cf) do {                                                  \
    uint4 _a = *(const uint4*)(rp);                                          \
    uint2 _b = *(const uint2*)((rp) + 4);                                    \
    FMIX_LO(acc[0], _a.x, cf);  FMIX_HI(acc[1], _a.x, cf);                   \
    FMIX_LO(acc[2], _a.y, cf);  FMIX_HI(acc[3], _a.y, cf);                   \
    FMIX_LO(acc[4], _a.z, cf);  FMIX_HI(acc[5], _a.z, cf);                   \
    FMIX_LO(acc[6], _a.w, cf);  FMIX_HI(acc[7], _a.w, cf);                   \
    FMIX_LO(acc[8], _b.x, cf);  FMIX_HI(acc[9], _b.x, cf);                   \
    FMIX_LO(acc[10], _b.y, cf); FMIX_HI(acc[11], _b.y, cf);                  \
} while (0)

// one packed row (24 ch in 12 u32 = 48B, 16B-aligned), scaled by cf
#define ROWH24(rp, cf) do {                                                  \
    uint4 _a = *(const uint4*)(rp);                                          \
    uint4 _b = *(const uint4*)((rp) + 4);                                    \
    uint4 _c = *(const uint4*)((rp) + 8);                                    \
    FMIX_LO(acc[0], _a.x, cf);  FMIX_HI(acc[1], _a.x, cf);                   \
    FMIX_LO(acc[2], _a.y, cf);  FMIX_HI(acc[3], _a.y, cf);                   \
    FMIX_LO(acc[4], _a.z, cf);  FMIX_HI(acc[5], _a.z, cf);                   \
    FMIX_LO(acc[6], _a.w, cf);  FMIX_HI(acc[7], _a.w, cf);                   \
    FMIX_LO(acc[8], _b.x, cf);  FMIX_HI(acc[9], _b.x, cf);                   \
    FMIX_LO(acc[10], _b.y, cf); FMIX_HI(acc[11], _b.y, cf);                  \
    FMIX_LO(acc[12], _b.z, cf); FMIX_HI(acc[13], _b.z, cf);                  \
    FMIX_LO(acc[14], _b.w, cf); FMIX_HI(acc[15], _b.w, cf);                  \
    FMIX_LO(acc[16], _c.x, cf); FMIX_HI(acc[17], _c.x, cf);                  \
    FMIX_LO(acc[18], _c.y, cf); FMIX_HI(acc[19], _c.y, cf);                  \
    FMIX_LO(acc[20], _c.z, cf); FMIX_HI(acc[21], _c.z, cf);                  \
    FMIX_LO(acc[22], _c.w, cf); FMIX_HI(acc[23], _c.w, cf);                  \
} while (0)

// Packed table layout per layer: [K*K][R] rows of ROWU u32 (2 halves each),
// R = G+9: row 0 = base (silu) w; rows 1..4 zero pad; rows 5..G+4 spline
// g=0..G-1 (scaler folded); rows G+5..G+8 zero pad.
// Spline rows for interval t (clamped to [-1,NINT]) are t+2+m, m=0..3.

// ---- fused KAN conv + 2x2 maxpool, sparse spline, packed-f16 tables -------
// Thread quad (4 lanes, sub = 2x2 conv position) per pooled output position.
// Conv grid is EXACT (B_BATCH*C*POS*4 threads): no early return in conv role.
// WITH_WF: blocks [CONVBLKS, CONVBLKS+135) compute Wf = w2 @ w1 instead.
template <int K, int NINT, int G, int N, int C, int HIN, int WIN, int HP,
          int WP, bool WITH_WF>
__global__ __launch_bounds__(256, 4) void kan_conv_pool(
    const float* __restrict__ in,
    const float* __restrict__ bw, const float* __restrict__ sws,
    const float* __restrict__ scl,
    float* __restrict__ out, float g0, float invh,
    const float* __restrict__ w1, const float* __restrict__ w2,
    float* __restrict__ Wf)
{
    constexpr int R = G + 9;
    constexpr int KK = K * K;
    constexpr int ROWU = (N == 12) ? 8 : 12;      // u32 per row (padded)
    constexpr int TBL = KK * R * ROWU;            // u32 total
    constexpr int POS = HP * WP;
    constexpr int CONVBLKS = B_BATCH * C * POS * 4 / 256;
    static_assert(N == 12 || N == 24, "layout");

    if (WITH_WF && (int)blockIdx.x >= CONVBLKS) {
        // Wf = w2 @ w1 (10 x 3456); 135*256 = 34560 exact
        int gid = ((int)blockIdx.x - CONVBLKS) * 256 + threadIdx.x;
        int n = gid / 3456, m = gid % 3456;
        float s = 0.f;
        for (int j = 0; j < 256; ++j)
            s = fmaf(w2[n * 256 + j], w1[j * 3456 + m], s);
        Wf[n * 3456 + m] = s;
        return;                          // whole block exits (block-uniform)
    }

    // ---- build packed f16 table in LDS from raw inputs
    __shared__ unsigned swp[TBL];
    for (int i = threadIdx.x; i < TBL; i += 256) swp[i] = 0u;
    __syncthreads();
    {
        unsigned short* sh = (unsigned short*)swp;
        for (int e = threadIdx.x; e < N * KK; e += 256) {
            int n = e / KK, k = e % KK;
            float sc = scl[n * KK + k];
            sh[((k * R + 0) * ROWU + (n >> 1)) * 2 + (n & 1)] =
                __half_as_ushort(__float2half(bw[n * KK + k]));
            for (int g = 0; g < G; ++g)
                sh[((k * R + 5 + g) * ROWU + (n >> 1)) * 2 + (n & 1)] =
                    __half_as_ushort(__float2half(sws[(n * KK + k) * G + g] * sc));
        }
    }
    __syncthreads();

    int tid = blockIdx.x * 256 + threadIdx.x;

    int sub = tid & 3;
    int rem = tid >> 2;
    int pos = rem % POS;
    int bc  = rem / POS;               // b*C + c
    int pi = pos / WP, pj = pos % WP;
    int p = 2 * pi + (sub >> 1);
    int q = 2 * pj + (sub & 1);

    const float* inp = in + bc * (HIN * WIN);

    float acc[N];
#pragma unroll
    for (int n = 0; n < N; ++n) acc[n] = 0.f;

#pragma unroll 1
    for (int dy = 0; dy < K; ++dy) {
#pragma unroll
        for (int dx = 0; dx < K; ++dx) {
            float v = inp[(p + dy) * WIN + (q + dx)];

            float s  = (v - g0) * invh;
            float sc = fminf(fmaxf(s, -1.0f), (float)NINT);  // sentinels hit pads
            float sf = floorf(sc);
            int   t  = (int)sf;
            float u  = sc - sf;                 // in [0,1]: coeffs stay finite
            float u2 = u * u, u3 = u2 * u;
            float um = 1.0f - u;
            float c0 = um * um * um * (1.0f / 6.0f);
            float c1 = (3.0f * u3 - 6.0f * u2 + 4.0f) * (1.0f / 6.0f);
            float c2 = (-3.0f * u3 + 3.0f * u2 + 3.0f * u + 1.0f) * (1.0f / 6.0f);
            float c3 = u3 * (1.0f / 6.0f);
            float sv = v / (1.0f + __expf(-v)); // silu

            const unsigned* wk = swp + (dy * K + dx) * (R * ROWU); // base row
            const unsigned* wt = wk + (t + 2) * ROWU;              // spline rows

            if constexpr (N == 12) {
                ROWH12(wk,            sv);
                ROWH12(wt + 0 * ROWU, c0);
                ROWH12(wt + 1 * ROWU, c1);
                ROWH12(wt + 2 * ROWU, c2);
                ROWH12(wt + 3 * ROWU, c3);
            } else {
                ROWH24(wk,            sv);
                ROWH24(wt + 0 * ROWU, c0);
                ROWH24(wt + 1 * ROWU, c1);
                ROWH24(wt + 2 * ROWU, c2);
                ROWH24(wt + 3 * ROWU, c3);
            }
        }
    }

    // 2x2 maxpool across the lane quad
#pragma unroll
    for (int n = 0; n < N; ++n) {
        acc[n] = fmaxf(acc[n], __shfl_xor(acc[n], 1, 64));
        acc[n] = fmaxf(acc[n], __shfl_xor(acc[n], 2, 64));
    }

    // each of the 4 lanes writes N/4 channels
    constexpr int NPL = N / 4;
    int n0 = sub * NPL;
    float* op = out + bc * (N * POS) + pos;
#pragma unroll
    for (int i = 0; i < NPL; ++i)
        op[(n0 + i) * POS] = acc[n0 + i];
}

// ---- final GEMV: out = x3 @ Wf^T + (b1 @ w2^T + b2) -----------------------
// grid 2560 waves exact; bias fold merged into the same wave reduction.
__global__ __launch_bounds__(256) void fc_kernel(
    const float* __restrict__ x3, const float* __restrict__ Wf,
    const float* __restrict__ b1, const float* __restrict__ w2,
    const float* __restrict__ b2, float* __restrict__ out)
{
    int wid  = (blockIdx.x * 256 + threadIdx.x) >> 6;
    int lane = threadIdx.x & 63;
    int b = wid / 10, n = wid - b * 10;
    const float4* xr = (const float4*)(x3 + b * 3456);
    const float4* wr = (const float4*)(Wf + n * 3456);
    float s = 0.f;
#pragma unroll
    for (int i = 0; i < 13; ++i) {       // 13*64*4 = 3328 floats
        float4 a = xr[lane + i * 64];
        float4 w = wr[lane + i * 64];
        s = fmaf(a.x, w.x, s); s = fmaf(a.y, w.y, s);
        s = fmaf(a.z, w.z, s); s = fmaf(a.w, w.w, s);
    }
    const float* xs  = x3 + b * 3456 + 3328;  // remainder 128 floats
    const float* wsp = Wf + n * 3456 + 3328;
    s = fmaf(xs[lane], wsp[lane], s);
    s = fmaf(xs[lane + 64], wsp[lane + 64], s);
    // folded bias: b1 @ w2[n,:]
    const float* w2r = w2 + n * 256;
    s = fmaf(b1[lane],       w2r[lane],       s);
    s = fmaf(b1[lane + 64],  w2r[lane + 64],  s);
    s = fmaf(b1[lane + 128], w2r[lane + 128], s);
    s = fmaf(b1[lane + 192], w2r[lane + 192], s);
    for (int o = 32; o; o >>= 1) s += __shfl_down(s, o, 64);
    if (lane == 0) out[wid] = s + b2[n];
}

// ---------------------------------------------------------------------------
extern "C" void kernel_launch(void* const* d_in, const int* in_sizes, int n_in,
                              void* d_out, int out_size, void* d_ws, size_t ws_size,
                              hipStream_t stream)
{
    (void)in_sizes; (void)n_in; (void)out_size; (void)ws_size;
    const float* x   = (const float*)d_in[0];
    const float* bw1 = (const float*)d_in[1];
    const float* sw1 = (const float*)d_in[2];
    const float* sc1 = (const float*)d_in[3];
    const float* bw2 = (const float*)d_in[4];
    const float* sw2 = (const float*)d_in[5];
    const float* sc2 = (const float*)d_in[6];
    const float* bw3 = (const float*)d_in[7];
    const float* sw3 = (const float*)d_in[8];
    const float* sc3 = (const float*)d_in[9];
    const float* w1  = (const float*)d_in[10];
    const float* b1  = (const float*)d_in[11];
    const float* w2  = (const float*)d_in[12];
    const float* b2  = (const float*)d_in[13];

    float* ws  = (float*)d_ws;
    float* Wf  = ws;              // 34560
    float* o1  = ws + 34560;      // 256*12*12*12 = 442368
    float* o2  = ws + 476928;     // 256*144*4*4  = 589824
    float* x3  = ws + 1066752;    // 256*3456     = 884736
    float* out = (float*)d_out;

    const float h1 = 2.0f / 5.0f, h2 = 2.0f / 10.0f;
    // layer1 + Wf: conv blocks 576 + wf blocks 135 = 711
    kan_conv_pool<5, 11, 8, 12, 1, 28, 28, 12, 12, true>
        <<<711, 256, 0, stream>>>(x, bw1, sw1, sc1, o1,
                                  -3.0f * h1 - 1.0f, 1.0f / h1, w1, w2, Wf);
    // layer2: K=4, NINT=16, G=13, N=12, C=12, 12x12 -> pooled 4x4
    kan_conv_pool<4, 16, 13, 12, 12, 12, 12, 4, 4, false>
        <<<768, 256, 0, stream>>>(o1, bw2, sw2, sc2, o2,
                                  -3.0f * h2 - 1.0f, 1.0f / h2,
                                  nullptr, nullptr, nullptr);
    // layer3: K=3, NINT=16, G=13, N=24, C=144, 4x4 -> pooled 1x1
    kan_conv_pool<3, 16, 13, 24, 144, 4, 4, 1, 1, false>
        <<<576, 256, 0, stream>>>(o2, bw3, sw3, sc3, x3,
                                  -3.0f * h2 - 1.0f, 1.0f / h2,
                                  nullptr, nullptr, nullptr);
    // fc with folded bias
    fc_kernel<<<640, 256, 0, stream>>>(x3, Wf, b1, w2, b2, out);
}

// Round 15
// 53.104 us; speedup vs baseline: 1.0963x; 1.0963x over previous
//
#include <hip/hip_runtime.h>
#include <math.h>

// ---------------------------------------------------------------------------
// SuperCKAN forward:
//   conv1 (k=5, grid5, n=12)  + pool -> (256,12,12,12)
//   conv2 (k=4, grid10, n=12) + pool -> (256,144,4,4)
//   conv3 (k=3, grid10, n=24) + pool -> (256,3456)
//   fc: x @ (w2@w1)^T + (b1@w2^T + b2) -> (256,10)
// All fp32.
//
// R14: cooperative launch REVERTED (R13: runtime rejected 768-block coop
// grid -> output never written; grid-stride at 512 would cost more in phase
// imbalance than the ~5us of gaps it saves). Back to R11's 4-launch
// structure (51.0us best).
// Single-variable probe of the LDS-issue model: the base (silu) weight row
// -- wave-uniform address, t-independent -- is read via SCALAR loads from
// global bw (uniform indices -> s_load, FMA uses SGPR weight operand)
// instead of LDS. LDS reads/elem: 15->12 (N=12), 30->24 (N=24). Spline path,
// accumulation order, table layout, launches: bit-identical to R11.
// ---------------------------------------------------------------------------

#define B_BATCH 256

// Weight LDS layout per layer: [K*K][R][N], R = G+9:
//   row 0: UNUSED (kept zero; base weights now read from global via s_load);
//   rows 1..4: zero pad; rows 5..G+4: spline g=0..G-1 (scaler folded);
//   rows G+5..G+8: zero pad.
// Spline rows for interval t (clamped to [-1, NINT]) are t+2+m, m=0..3.

// ---- fused KAN conv + 2x2 maxpool, sparse spline, in-LDS table build ------
// Thread quad (4 lanes, sub = 2x2 conv position) per pooled output position.
// Conv grid is EXACT (B_BATCH*C*POS*4 threads): no early return in conv role.
// WITH_WF: blocks [CONVBLKS, CONVBLKS+135) compute Wf = w2 @ w1 instead.
template <int K, int NINT, int G, int N, int C, int HIN, int WIN, int HP,
          int WP, bool WITH_WF>
__global__ __launch_bounds__(256, 4) void kan_conv_pool(
    const float* __restrict__ in,
    const float* __restrict__ bw, const float* __restrict__ sws,
    const float* __restrict__ scl,
    float* __restrict__ out, float g0, float invh,
    const float* __restrict__ w1, const float* __restrict__ w2,
    float* __restrict__ Wf)
{
    constexpr int R = G + 9;
    constexpr int POS = HP * WP;
    constexpr int WSZ = K * K * R * N;
    constexpr int KK = K * K;
    constexpr int CONVBLKS = B_BATCH * C * POS * 4 / 256;
    static_assert((N % 4) == 0, "alignment");

    if (WITH_WF && (int)blockIdx.x >= CONVBLKS) {
        // Wf = w2 @ w1 (10 x 3456); 135*256 = 34560 exact
        int gid = ((int)blockIdx.x - CONVBLKS) * 256 + threadIdx.x;
        int n = gid / 3456, m = gid % 3456;
        float s = 0.f;
        for (int j = 0; j < 256; ++j)
            s = fmaf(w2[n * 256 + j], w1[j * 3456 + m], s);
        Wf[n * 3456 + m] = s;
        return;                          // whole block exits (block-uniform)
    }

    // ---- build spline table in LDS from raw inputs (base row stays zero)
    __shared__ float sw[WSZ];
    for (int i = threadIdx.x; i < WSZ; i += 256) sw[i] = 0.f;
    __syncthreads();
    for (int e = threadIdx.x; e < N * KK; e += 256) {
        int n = e / KK, k = e % KK;
        float sc = scl[n * KK + k];
        for (int g = 0; g < G; ++g)
            sw[(k * R + 5 + g) * N + n] = sws[(n * KK + k) * G + g] * sc;
    }
    __syncthreads();

    int tid = blockIdx.x * 256 + threadIdx.x;

    int sub = tid & 3;
    int rem = tid >> 2;
    int pos = rem % POS;
    int bc  = rem / POS;               // b*C + c
    int pi = pos / WP, pj = pos % WP;
    int p = 2 * pi + (sub >> 1);
    int q = 2 * pj + (sub & 1);

    const float* inp = in + bc * (HIN * WIN);

    float acc[N];
#pragma unroll
    for (int n = 0; n < N; ++n) acc[n] = 0.f;

#pragma unroll 1
    for (int dy = 0; dy < K; ++dy) {
#pragma unroll
        for (int dx = 0; dx < K; ++dx) {
            float v = inp[(p + dy) * WIN + (q + dx)];

            float s  = (v - g0) * invh;
            float sc = fminf(fmaxf(s, -1.0f), (float)NINT);  // sentinels hit pads
            float sf = floorf(sc);
            int   t  = (int)sf;
            float u  = sc - sf;                 // in [0,1]: coeffs stay finite
            float u2 = u * u, u3 = u2 * u;
            float um = 1.0f - u;
            float c0 = um * um * um * (1.0f / 6.0f);
            float c1 = (3.0f * u3 - 6.0f * u2 + 4.0f) * (1.0f / 6.0f);
            float c2 = (-3.0f * u3 + 3.0f * u2 + 3.0f * u + 1.0f) * (1.0f / 6.0f);
            float c3 = u3 * (1.0f / 6.0f);
            float sv = v / (1.0f + __expf(-v)); // silu

            int kk = dy * K + dx;

            // base (silu) row: wave-uniform scalar loads from global (s_load;
            // FMA consumes the weight as its single SGPR operand)
#pragma unroll
            for (int n = 0; n < N; ++n)
                acc[n] = fmaf(sv, bw[n * KK + kk], acc[n]);

            const float* wt = sw + kk * (R * N) + (t + 2) * N; // spline rows

#pragma unroll
            for (int n4 = 0; n4 < N / 4; ++n4) {
                float4 w0 = ((const float4*)(wt + 0 * N))[n4];
                float4 w1_ = ((const float4*)(wt + 1 * N))[n4];
                float4 w2_ = ((const float4*)(wt + 2 * N))[n4];
                float4 w3_ = ((const float4*)(wt + 3 * N))[n4];
                float a0 = acc[n4 * 4 + 0], a1 = acc[n4 * 4 + 1];
                float a2 = acc[n4 * 4 + 2], a3 = acc[n4 * 4 + 3];
                a0 = fmaf(c0, w0.x, a0); a1 = fmaf(c0, w0.y, a1);
                a2 = fmaf(c0, w0.z, a2); a3 = fmaf(c0, w0.w, a3);
                a0 = fmaf(c1, w1_.x, a0); a1 = fmaf(c1, w1_.y, a1);
                a2 = fmaf(c1, w1_.z, a2); a3 = fmaf(c1, w1_.w, a3);
                a0 = fmaf(c2, w2_.x, a0); a1 = fmaf(c2, w2_.y, a1);
                a2 = fmaf(c2, w2_.z, a2); a3 = fmaf(c2, w2_.w, a3);
                a0 = fmaf(c3, w3_.x, a0); a1 = fmaf(c3, w3_.y, a1);
                a2 = fmaf(c3, w3_.z, a2); a3 = fmaf(c3, w3_.w, a3);
                acc[n4 * 4 + 0] = a0; acc[n4 * 4 + 1] = a1;
                acc[n4 * 4 + 2] = a2; acc[n4 * 4 + 3] = a3;
            }
        }
    }

    // 2x2 maxpool across the lane quad
#pragma unroll
    for (int n = 0; n < N; ++n) {
        acc[n] = fmaxf(acc[n], __shfl_xor(acc[n], 1, 64));
        acc[n] = fmaxf(acc[n], __shfl_xor(acc[n], 2, 64));
    }

    // each of the 4 lanes writes N/4 channels
    constexpr int NPL = N / 4;
    int n0 = sub * NPL;
    float* op = out + bc * (N * POS) + pos;
#pragma unroll
    for (int i = 0; i < NPL; ++i)
        op[(n0 + i) * POS] = acc[n0 + i];
}

// ---- final GEMV: out = x3 @ Wf^T + (b1 @ w2^T + b2) -----------------------
// grid 2560 waves exact; bias fold merged into the same wave reduction.
__global__ __launch_bounds__(256) void fc_kernel(
    const float* __restrict__ x3, const float* __restrict__ Wf,
    const float* __restrict__ b1, const float* __restrict__ w2,
    const float* __restrict__ b2, float* __restrict__ out)
{
    int wid  = (blockIdx.x * 256 + threadIdx.x) >> 6;
    int lane = threadIdx.x & 63;
    int b = wid / 10, n = wid - b * 10;
    const float4* xr = (const float4*)(x3 + b * 3456);
    const float4* wr = (const float4*)(Wf + n * 3456);
    float s = 0.f;
#pragma unroll
    for (int i = 0; i < 13; ++i) {       // 13*64*4 = 3328 floats
        float4 a = xr[lane + i * 64];
        float4 w = wr[lane + i * 64];
        s = fmaf(a.x, w.x, s); s = fmaf(a.y, w.y, s);
        s = fmaf(a.z, w.z, s); s = fmaf(a.w, w.w, s);
    }
    const float* xs  = x3 + b * 3456 + 3328;  // remainder 128 floats
    const float* wsp = Wf + n * 3456 + 3328;
    s = fmaf(xs[lane], wsp[lane], s);
    s = fmaf(xs[lane + 64], wsp[lane + 64], s);
    // folded bias: b1 @ w2[n,:]
    const float* w2r = w2 + n * 256;
    s = fmaf(b1[lane],       w2r[lane],       s);
    s = fmaf(b1[lane + 64],  w2r[lane + 64],  s);
    s = fmaf(b1[lane + 128], w2r[lane + 128], s);
    s = fmaf(b1[lane + 192], w2r[lane + 192], s);
    for (int o = 32; o; o >>= 1) s += __shfl_down(s, o, 64);
    if (lane == 0) out[wid] = s + b2[n];
}

// ---------------------------------------------------------------------------
extern "C" void kernel_launch(void* const* d_in, const int* in_sizes, int n_in,
                              void* d_out, int out_size, void* d_ws, size_t ws_size,
                              hipStream_t stream)
{
    (void)in_sizes; (void)n_in; (void)out_size; (void)ws_size;
    const float* x   = (const float*)d_in[0];
    const float* bw1 = (const float*)d_in[1];
    const float* sw1 = (const float*)d_in[2];
    const float* sc1 = (const float*)d_in[3];
    const float* bw2 = (const float*)d_in[4];
    const float* sw2 = (const float*)d_in[5];
    const float* sc2 = (const float*)d_in[6];
    const float* bw3 = (const float*)d_in[7];
    const float* sw3 = (const float*)d_in[8];
    const float* sc3 = (const float*)d_in[9];
    const float* w1  = (const float*)d_in[10];
    const float* b1  = (const float*)d_in[11];
    const float* w2  = (const float*)d_in[12];
    const float* b2  = (const float*)d_in[13];

    float* ws  = (float*)d_ws;
    float* Wf  = ws;              // 34560
    float* o1  = ws + 34560;      // 256*12*12*12 = 442368
    float* o2  = ws + 476928;     // 256*144*4*4  = 589824
    float* x3  = ws + 1066752;    // 256*3456     = 884736
    float* out = (float*)d_out;

    const float h1 = 2.0f / 5.0f, h2 = 2.0f / 10.0f;
    // layer1 + Wf: conv blocks 576 + wf blocks 135 = 711
    kan_conv_pool<5, 11, 8, 12, 1, 28, 28, 12, 12, true>
        <<<711, 256, 0, stream>>>(x, bw1, sw1, sc1, o1,
                                  -3.0f * h1 - 1.0f, 1.0f / h1, w1, w2, Wf);
    // layer2: K=4, NINT=16, G=13, N=12, C=12, 12x12 -> pooled 4x4
    kan_conv_pool<4, 16, 13, 12, 12, 12, 12, 4, 4, false>
        <<<768, 256, 0, stream>>>(o1, bw2, sw2, sc2, o2,
                                  -3.0f * h2 - 1.0f, 1.0f / h2,
                                  nullptr, nullptr, nullptr);
    // layer3: K=3, NINT=16, G=13, N=24, C=144, 4x4 -> pooled 1x1
    kan_conv_pool<3, 16, 13, 24, 144, 4, 4, 1, 1, false>
        <<<576, 256, 0, stream>>>(o2, bw3, sw3, sc3, x3,
                                  -3.0f * h2 - 1.0f, 1.0f / h2,
                                  nullptr, nullptr, nullptr);
    // fc with folded bias
    fc_kernel<<<640, 256, 0, stream>>>(x3, Wf, b1, w2, b2, out);
}

// Round 16
// 51.051 us; speedup vs baseline: 1.1404x; 1.0402x over previous
//
#include <hip/hip_runtime.h>
#include <math.h>

// ---------------------------------------------------------------------------
// SuperCKAN forward:
//   conv1 (k=5, grid5, n=12)  + pool -> (256,12,12,12)
//   conv2 (k=4, grid10, n=12) + pool -> (256,144,4,4)
//   conv3 (k=3, grid10, n=24) + pool -> (256,3456)
//   fc: x @ (w2@w1)^T + (b1@w2^T + b2) -> (256,10)
// All fp32.
//
// R15: FINAL REVERT to R11 (51.0us, session best). R14's clean probe (base
// row via s_load, -20% LDS reads) was flat/negative -> LDS-issue model
// falsified; convs are latency/mixed-bound and every pipe substitution
// (VMEM split R6, occupancy R8, f16 R7/R9/R10/R12, coop R13, s_load R14)
// regressed. The R11 form -- plain fp32 float4 LDS reads + compiler-
// scheduled fmac, 4 launches, in-LDS table build, Wf overlapped with conv1,
// folded-bias fc -- is the empirical optimum of this design space.
// Design: zero-padded tables [base][4 pad][G][4 pad], s clamped to [-1,NINT]
// so boundary values read pad rows (no masking); sparse 4-basis cubic spline.
// ---------------------------------------------------------------------------

#define B_BATCH 256

// Weight LDS layout per layer: [K*K][R][N], R = G+9:
//   row 0: base (silu) w; rows 1..4: zero pad; rows 5..G+4: spline g=0..G-1
//   (scaler folded); rows G+5..G+8: zero pad.
// Spline rows for interval t (clamped to [-1, NINT]) are t+2+m, m=0..3.

// ---- fused KAN conv + 2x2 maxpool, sparse spline, in-LDS table build ------
// Thread quad (4 lanes, sub = 2x2 conv position) per pooled output position.
// Conv grid is EXACT (B_BATCH*C*POS*4 threads): no early return in conv role.
// WITH_WF: blocks [CONVBLKS, CONVBLKS+135) compute Wf = w2 @ w1 instead.
template <int K, int NINT, int G, int N, int C, int HIN, int WIN, int HP,
          int WP, bool WITH_WF>
__global__ __launch_bounds__(256, 4) void kan_conv_pool(
    const float* __restrict__ in,
    const float* __restrict__ bw, const float* __restrict__ sws,
    const float* __restrict__ scl,
    float* __restrict__ out, float g0, float invh,
    const float* __restrict__ w1, const float* __restrict__ w2,
    float* __restrict__ Wf)
{
    constexpr int R = G + 9;
    constexpr int POS = HP * WP;
    constexpr int WSZ = K * K * R * N;
    constexpr int KK = K * K;
    constexpr int CONVBLKS = B_BATCH * C * POS * 4 / 256;
    static_assert((N % 4) == 0, "alignment");

    if (WITH_WF && (int)blockIdx.x >= CONVBLKS) {
        // Wf = w2 @ w1 (10 x 3456); 135*256 = 34560 exact
        int gid = ((int)blockIdx.x - CONVBLKS) * 256 + threadIdx.x;
        int n = gid / 3456, m = gid % 3456;
        float s = 0.f;
        for (int j = 0; j < 256; ++j)
            s = fmaf(w2[n * 256 + j], w1[j * 3456 + m], s);
        Wf[n * 3456 + m] = s;
        return;                          // whole block exits (block-uniform)
    }

    // ---- build weight table in LDS from raw inputs (bit-identical to prep)
    __shared__ float sw[WSZ];
    for (int i = threadIdx.x; i < WSZ; i += 256) sw[i] = 0.f;
    __syncthreads();
    for (int e = threadIdx.x; e < N * KK; e += 256) {
        int n = e / KK, k = e % KK;
        float sc = scl[n * KK + k];
        sw[(k * R + 0) * N + n] = bw[n * KK + k];
        for (int g = 0; g < G; ++g)
            sw[(k * R + 5 + g) * N + n] = sws[(n * KK + k) * G + g] * sc;
    }
    __syncthreads();

    int tid = blockIdx.x * 256 + threadIdx.x;

    int sub = tid & 3;
    int rem = tid >> 2;
    int pos = rem % POS;
    int bc  = rem / POS;               // b*C + c
    int pi = pos / WP, pj = pos % WP;
    int p = 2 * pi + (sub >> 1);
    int q = 2 * pj + (sub & 1);

    const float* inp = in + bc * (HIN * WIN);

    float acc[N];
#pragma unroll
    for (int n = 0; n < N; ++n) acc[n] = 0.f;

#pragma unroll 1
    for (int dy = 0; dy < K; ++dy) {
#pragma unroll
        for (int dx = 0; dx < K; ++dx) {
            float v = inp[(p + dy) * WIN + (q + dx)];

            float s  = (v - g0) * invh;
            float sc = fminf(fmaxf(s, -1.0f), (float)NINT);  // sentinels hit pads
            float sf = floorf(sc);
            int   t  = (int)sf;
            float u  = sc - sf;                 // in [0,1]: coeffs stay finite
            float u2 = u * u, u3 = u2 * u;
            float um = 1.0f - u;
            float c0 = um * um * um * (1.0f / 6.0f);
            float c1 = (3.0f * u3 - 6.0f * u2 + 4.0f) * (1.0f / 6.0f);
            float c2 = (-3.0f * u3 + 3.0f * u2 + 3.0f * u + 1.0f) * (1.0f / 6.0f);
            float c3 = u3 * (1.0f / 6.0f);
            float sv = v / (1.0f + __expf(-v)); // silu

            const float* wk = sw + (dy * K + dx) * (R * N);  // base row (uniform)
            const float* wt = wk + (t + 2) * N;              // spline row block

#pragma unroll
            for (int n4 = 0; n4 < N / 4; ++n4) {
                float4 wb = ((const float4*)wk)[n4];
                float4 w0 = ((const float4*)(wt + 0 * N))[n4];
                float4 w1_ = ((const float4*)(wt + 1 * N))[n4];
                float4 w2_ = ((const float4*)(wt + 2 * N))[n4];
                float4 w3_ = ((const float4*)(wt + 3 * N))[n4];
                float a0 = acc[n4 * 4 + 0], a1 = acc[n4 * 4 + 1];
                float a2 = acc[n4 * 4 + 2], a3 = acc[n4 * 4 + 3];
                a0 = fmaf(sv, wb.x, a0); a1 = fmaf(sv, wb.y, a1);
                a2 = fmaf(sv, wb.z, a2); a3 = fmaf(sv, wb.w, a3);
                a0 = fmaf(c0, w0.x, a0); a1 = fmaf(c0, w0.y, a1);
                a2 = fmaf(c0, w0.z, a2); a3 = fmaf(c0, w0.w, a3);
                a0 = fmaf(c1, w1_.x, a0); a1 = fmaf(c1, w1_.y, a1);
                a2 = fmaf(c1, w1_.z, a2); a3 = fmaf(c1, w1_.w, a3);
                a0 = fmaf(c2, w2_.x, a0); a1 = fmaf(c2, w2_.y, a1);
                a2 = fmaf(c2, w2_.z, a2); a3 = fmaf(c2, w2_.w, a3);
                a0 = fmaf(c3, w3_.x, a0); a1 = fmaf(c3, w3_.y, a1);
                a2 = fmaf(c3, w3_.z, a2); a3 = fmaf(c3, w3_.w, a3);
                acc[n4 * 4 + 0] = a0; acc[n4 * 4 + 1] = a1;
                acc[n4 * 4 + 2] = a2; acc[n4 * 4 + 3] = a3;
            }
        }
    }

    // 2x2 maxpool across the lane quad
#pragma unroll
    for (int n = 0; n < N; ++n) {
        acc[n] = fmaxf(acc[n], __shfl_xor(acc[n], 1, 64));
        acc[n] = fmaxf(acc[n], __shfl_xor(acc[n], 2, 64));
    }

    // each of the 4 lanes writes N/4 channels
    constexpr int NPL = N / 4;
    int n0 = sub * NPL;
    float* op = out + bc * (N * POS) + pos;
#pragma unroll
    for (int i = 0; i < NPL; ++i)
        op[(n0 + i) * POS] = acc[n0 + i];
}

// ---- final GEMV: out = x3 @ Wf^T + (b1 @ w2^T + b2) -----------------------
// grid 2560 waves exact; bias fold merged into the same wave reduction.
__global__ __launch_bounds__(256) void fc_kernel(
    const float* __restrict__ x3, const float* __restrict__ Wf,
    const float* __restrict__ b1, const float* __restrict__ w2,
    const float* __restrict__ b2, float* __restrict__ out)
{
    int wid  = (blockIdx.x * 256 + threadIdx.x) >> 6;
    int lane = threadIdx.x & 63;
    int b = wid / 10, n = wid - b * 10;
    const float4* xr = (const float4*)(x3 + b * 3456);
    const float4* wr = (const float4*)(Wf + n * 3456);
    float s = 0.f;
#pragma unroll
    for (int i = 0; i < 13; ++i) {       // 13*64*4 = 3328 floats
        float4 a = xr[lane + i * 64];
        float4 w = wr[lane + i * 64];
        s = fmaf(a.x, w.x, s); s = fmaf(a.y, w.y, s);
        s = fmaf(a.z, w.z, s); s = fmaf(a.w, w.w, s);
    }
    const float* xs  = x3 + b * 3456 + 3328;  // remainder 128 floats
    const float* wsp = Wf + n * 3456 + 3328;
    s = fmaf(xs[lane], wsp[lane], s);
    s = fmaf(xs[lane + 64], wsp[lane + 64], s);
    // folded bias: b1 @ w2[n,:]
    const float* w2r = w2 + n * 256;
    s = fmaf(b1[lane],       w2r[lane],       s);
    s = fmaf(b1[lane + 64],  w2r[lane + 64],  s);
    s = fmaf(b1[lane + 128], w2r[lane + 128], s);
    s = fmaf(b1[lane + 192], w2r[lane + 192], s);
    for (int o = 32; o; o >>= 1) s += __shfl_down(s, o, 64);
    if (lane == 0) out[wid] = s + b2[n];
}

// ---------------------------------------------------------------------------
extern "C" void kernel_launch(void* const* d_in, const int* in_sizes, int n_in,
                              void* d_out, int out_size, void* d_ws, size_t ws_size,
                              hipStream_t stream)
{
    (void)in_sizes; (void)n_in; (void)out_size; (void)ws_size;
    const float* x   = (const float*)d_in[0];
    const float* bw1 = (const float*)d_in[1];
    const float* sw1 = (const float*)d_in[2];
    const float* sc1 = (const float*)d_in[3];
    const float* bw2 = (const float*)d_in[4];
    const float* sw2 = (const float*)d_in[5];
    const float* sc2 = (const float*)d_in[6];
    const float* bw3 = (const float*)d_in[7];
    const float* sw3 = (const float*)d_in[8];
    const float* sc3 = (const float*)d_in[9];
    const float* w1  = (const float*)d_in[10];
    const float* b1  = (const float*)d_in[11];
    const float* w2  = (const float*)d_in[12];
    const float* b2  = (const float*)d_in[13];

    float* ws  = (float*)d_ws;
    float* Wf  = ws;              // 34560
    float* o1  = ws + 34560;      // 256*12*12*12 = 442368
    float* o2  = ws + 476928;     // 256*144*4*4  = 589824
    float* x3  = ws + 1066752;    // 256*3456     = 884736
    float* out = (float*)d_out;

    const float h1 = 2.0f / 5.0f, h2 = 2.0f / 10.0f;
    // layer1 + Wf: conv blocks 576 + wf blocks 135 = 711
    kan_conv_pool<5, 11, 8, 12, 1, 28, 28, 12, 12, true>
        <<<711, 256, 0, stream>>>(x, bw1, sw1, sc1, o1,
                                  -3.0f * h1 - 1.0f, 1.0f / h1, w1, w2, Wf);
    // layer2: K=4, NINT=16, G=13, N=12, C=12, 12x12 -> pooled 4x4
    kan_conv_pool<4, 16, 13, 12, 12, 12, 12, 4, 4, false>
        <<<768, 256, 0, stream>>>(o1, bw2, sw2, sc2, o2,
                                  -3.0f * h2 - 1.0f, 1.0f / h2,
                                  nullptr, nullptr, nullptr);
    // layer3: K=3, NINT=16, G=13, N=24, C=144, 4x4 -> pooled 1x1
    kan_conv_pool<3, 16, 13, 24, 144, 4, 4, 1, 1, false>
        <<<576, 256, 0, stream>>>(o2, bw3, sw3, sc3, x3,
                                  -3.0f * h2 - 1.0f, 1.0f / h2,
                                  nullptr, nullptr, nullptr);
    // fc with folded bias
    fc_kernel<<<640, 256, 0, stream>>>(x3, Wf, b1, w2, b2, out);
}